// Round 10
// baseline (67.113 us; speedup 1.0000x reference)
//
#include <hip/hip_runtime.h>
#include <math.h>

#define B_  16
#define F_  64
#define C_  64
#define M_  512
#define OC_ 32

typedef float vf4 __attribute__((ext_vector_type(4)));   // clang-native for nt ld/st

// ---------------------------------------------------------------------------
// k1 v4: s[b,c,m] = mean_f x[b,f,c,m], m-split 4-ways for occupancy.
// x is read via NON-TEMPORAL loads: x has zero reuse (one read per replay)
// and x+A (268 MB) doesn't fit L3 (256 MB). Keeping x out of L3 lets A
// (134 MB) stay resident across graph replays for k2.
// ---------------------------------------------------------------------------
__global__ __launch_bounds__(128, 6) void k1_mean(
    const float* __restrict__ x,
    float* __restrict__ s_out, float* __restrict__ rpart)
{
    const int gid = blockIdx.x;        // bc*4 + q
    const int q   = gid & 3;
    const int bc  = gid >> 2;
    const int b   = bc >> 6;
    const int c   = bc & 63;
    const int t   = threadIdx.x;
    const int tf  = t >> 5;            // 0..3 -> f chunk
    const int tm  = t & 31;            // float4 column within window
    const int m4  = (q << 5) + tm;     // global float4 index 0..127

    const size_t rowbase = ((size_t)b * F_ * C_ + c) * M_;   // + f*C*M
    float ax = 0.f, ay = 0.f, az = 0.f, aw = 0.f;
    #pragma unroll 8
    for (int j = 0; j < 16; ++j) {
        const int f = (tf << 4) + j;
        const vf4 v = __builtin_nontemporal_load(
            ((const vf4*)(x + rowbase + (size_t)f * C_ * M_)) + m4);
        ax += v.x; ay += v.y; az += v.z; aw += v.w;
    }

    __shared__ float4 red[4][32];
    red[tf][tm] = make_float4(ax, ay, az, aw);
    __syncthreads();

    if (tf == 0) {                     // lanes 0..31 of wave 0
        const float4 r1 = red[1][tm], r2 = red[2][tm], r3 = red[3][tm];
        const float inv_f = 1.0f / (float)F_;
        float4 sv;
        sv.x = (ax + r1.x + r2.x + r3.x) * inv_f;
        sv.y = (ay + r1.y + r2.y + r3.y) * inv_f;
        sv.z = (az + r1.z + r2.z + r3.z) * inv_f;
        sv.w = (aw + r1.w + r2.w + r3.w) * inv_f;
        ((float4*)(s_out + (size_t)bc * M_))[m4] = sv;

        float p = sv.x + sv.y + sv.z + sv.w;
        #pragma unroll
        for (int off = 16; off > 0; off >>= 1) p += __shfl_xor(p, off);
        if (t == 0) rpart[gid] = p;
    }
}

// ---------------------------------------------------------------------------
// k2 v3: per-(b,m) block of 256 threads (4 waves share one A tile).
// (unchanged from R3 — tied-best; A should now be L3-resident)
// ---------------------------------------------------------------------------
__global__ __launch_bounds__(256) void k2_laplace(
    const float* __restrict__ A, const float* __restrict__ phys,
    const float* __restrict__ kappa_p, const float* __restrict__ alpha_p,
    const float* __restrict__ s_in, const float* __restrict__ rpart,
    const float* __restrict__ w1, const float* __restrict__ b1,
    const float* __restrict__ w2, const float* __restrict__ b2,
    float* __restrict__ snew)
{
    __shared__ float Al[C_ * 65];
    __shared__ float sl[C_];
    __shared__ float redD[4 * C_];
    __shared__ float redA[4 * C_];

    const int bm = blockIdx.x;     // b*M + m
    const int b  = bm >> 9;
    const int m  = bm & 511;
    const int t  = threadIdx.x;    // 0..255
    const int c  = t & 63;
    const int q  = t >> 6;

    // r-MLP preamble: overlapped by the compiler with the A staging below
    float r = 0.f;
    if (t < 64) {
        const float4 rp = ((const float4*)rpart)[b * C_ + t];
        const float rin = (rp.x + rp.y + rp.z + rp.w) * (1.0f / (float)M_);
        r = b2[0];
        #pragma unroll
        for (int j = 0; j < 16; ++j) {
            float h = rin * w1[j] + b1[j];        // w1 is (16,1)
            h = (h > 0.f) ? h : (expf(h) - 1.f);  // ELU(alpha=1)
            r += h * w2[j];
        }
        sl[t] = s_in[((size_t)b * C_ + t) * M_ + m];
    }

    // stage A[b,m,:,:] (4096 f32) via coalesced float4 loads, pad stride 65
    const float4* Ap = (const float4*)(A + (size_t)bm * (C_ * C_));
    #pragma unroll
    for (int i = 0; i < 4; ++i) {
        const int idx = t + i * 256;       // float4 index 0..1023
        const float4 v = Ap[idx];
        const int row = idx >> 4;          // 16 float4 per row
        const int col = (idx & 15) << 2;
        float* dst = &Al[row * 65 + col];
        dst[0] = v.x; dst[1] = v.y; dst[2] = v.z; dst[3] = v.w;
    }
    __syncthreads();

    // quarter-reductions: q selects 16 of the 64 summation indices
    float dpart = 0.f, apart = 0.f;
    const int j0 = q << 4;
    #pragma unroll
    for (int j = 0; j < 16; ++j) {
        dpart += Al[c * 65 + (j0 + j)];              // row c (deg)
        apart += Al[(j0 + j) * 65 + c] * sl[j0 + j]; // col c (A^T s)
    }
    redD[(q << 6) + c] = dpart;
    redA[(q << 6) + c] = apart;
    __syncthreads();

    if (t < 64) {
        const float deg = redD[t] + redD[64 + t] + redD[128 + t] + redD[192 + t];
        const float As  = redA[t] + redA[64 + t] + redA[128 + t] + redA[192 + t];
        const float sval = sl[t];
        const float k    = log1pf(expf(kappa_p[0]));   // softplus
        const float Ls   = deg * sval - As;
        const float val  = sval - k * Ls
                         + (r + alpha_p[0] * phys[((size_t)b * C_ + t) * M_ + m]);
        snew[((size_t)b * C_ + t) * M_ + m] = val;
    }
}

// ---------------------------------------------------------------------------
// k3 v2: out[b,o,c,m] = s_new[b,c,m]*pw[o] + pb[o], NON-TEMPORAL stores.
// (unchanged from R9 — proven −9.2 µs)
// ---------------------------------------------------------------------------
__global__ __launch_bounds__(256) void k3_expand(
    const float* __restrict__ snew,
    const float* __restrict__ pw, const float* __restrict__ pb,
    float* __restrict__ out)
{
    const int n4 = (B_ * OC_ * C_ * M_) / 4;   // 4,194,304
    for (int i = blockIdx.x * blockDim.x + threadIdx.x; i < n4;
         i += gridDim.x * blockDim.x) {
        const int m4 = i & 127;          // M/4 = 128
        const int c  = (i >> 7) & 63;
        const int o  = (i >> 13) & 31;
        const int b  = i >> 18;
        const float4 v = ((const float4*)snew)[(((b << 6) + c) << 7) + m4];
        const float w  = pw[o];
        const float bb = pb[o];
        vf4 r;
        r.x = v.x * w + bb; r.y = v.y * w + bb;
        r.z = v.z * w + bb; r.w = v.w * w + bb;
        __builtin_nontemporal_store(r, ((vf4*)out) + i);
    }
}

extern "C" void kernel_launch(void* const* d_in, const int* in_sizes, int n_in,
                              void* d_out, int out_size, void* d_ws, size_t ws_size,
                              hipStream_t stream)
{
    const float* x     = (const float*)d_in[0];
    const float* A     = (const float*)d_in[1];
    const float* phys  = (const float*)d_in[2];
    const float* kappa = (const float*)d_in[3];
    const float* alpha = (const float*)d_in[4];
    const float* w1    = (const float*)d_in[5];
    const float* b1    = (const float*)d_in[6];
    const float* w2    = (const float*)d_in[7];
    const float* b2    = (const float*)d_in[8];
    const float* pw    = (const float*)d_in[9];
    const float* pb    = (const float*)d_in[10];
    float* out = (float*)d_out;

    float* ws    = (float*)d_ws;
    float* s     = ws;                            // B*C*M
    float* snew  = ws + (size_t)B_ * C_ * M_;     // B*C*M
    float* rpart = ws + (size_t)2 * B_ * C_ * M_; // B*C*4 (16B-aligned)

    k1_mean<<<B_ * C_ * 4, 128, 0, stream>>>(x, s, rpart);
    k2_laplace<<<B_ * M_, 256, 0, stream>>>(A, phys, kappa, alpha, s, rpart,
                                            w1, b1, w2, b2, snew);
    k3_expand<<<2048, 256, 0, stream>>>(snew, pw, pb, out);
}